// Round 5
// baseline (437.132 us; speedup 1.0000x reference)
//
#include <hip/hip_runtime.h>

#define NN 4096
#define R_RANK 10

typedef __bf16 bf16x8 __attribute__((ext_vector_type(8)));
typedef float floatx4 __attribute__((ext_vector_type(4)));

__device__ __forceinline__ unsigned short f2bf(float f) {
    union { float f; unsigned int u; } v; v.f = f;
    unsigned int r = v.u + 0x7FFFu + ((v.u >> 16) & 1u);   // RNE
    return (unsigned short)(r >> 16);
}
// async global->LDS, 16B per lane; LDS dest = wave-uniform base + lane*16
__device__ __forceinline__ void gll16(const void* g, void* l) {
    __builtin_amdgcn_global_load_lds(
        (const __attribute__((address_space(1))) unsigned int*)g,
        (__attribute__((address_space(3))) unsigned int*)l, 16, 0, 0);
}

// ---------------------------------------------------------------------------
// Adjacency: row stats (4 rows/block; zeroes deg+pooled) -> col degree -> AnT
// ---------------------------------------------------------------------------
__global__ __launch_bounds__(256) void row_stats_kernel(
    const float* __restrict__ nv1, const float* __restrict__ nv2,
    float* __restrict__ rowmax, float* __restrict__ rowsum,
    float* __restrict__ deg, float* __restrict__ pooled)
{
    const int i0 = blockIdx.x * 4;
    const int tid = threadIdx.x;
    if (blockIdx.x < 16) deg[blockIdx.x * 256 + tid] = 0.f;
    if (blockIdx.x >= 16 && blockIdx.x < 18) pooled[(blockIdx.x - 16) * 256 + tid] = 0.f;
    __shared__ float a[4][R_RANK];
    if (tid < 4 * R_RANK) a[tid / R_RANK][tid % R_RANK] = nv1[i0 * R_RANK + tid];
    __syncthreads();

    float s[4][16];
    float mx[4] = {0.f, 0.f, 0.f, 0.f};   // relu >= 0
    #pragma unroll
    for (int t = 0; t < 16; ++t) {
        const int j = t * 256 + tid;
        float v[R_RANK];
        #pragma unroll
        for (int r = 0; r < R_RANK; ++r) v[r] = nv2[r * NN + j];
        #pragma unroll
        for (int q = 0; q < 4; ++q) {
            float acc = 0.f;
            #pragma unroll
            for (int r = 0; r < R_RANK; ++r) acc = fmaf(a[q][r], v[r], acc);
            acc = fmaxf(acc, 0.f);
            s[q][t] = acc;
            mx[q] = fmaxf(mx[q], acc);
        }
    }
    __shared__ float red[4][4];
    #pragma unroll
    for (int q = 0; q < 4; ++q) {
        float m = mx[q];
        #pragma unroll
        for (int off = 32; off > 0; off >>= 1) m = fmaxf(m, __shfl_down(m, off, 64));
        if ((tid & 63) == 0) red[q][tid >> 6] = m;
    }
    __syncthreads();
    #pragma unroll
    for (int q = 0; q < 4; ++q)
        mx[q] = fmaxf(fmaxf(red[q][0], red[q][1]), fmaxf(red[q][2], red[q][3]));
    __syncthreads();
    float sm[4] = {0.f, 0.f, 0.f, 0.f};
    #pragma unroll
    for (int t = 0; t < 16; ++t)
        #pragma unroll
        for (int q = 0; q < 4; ++q) sm[q] += __expf(s[q][t] - mx[q]);
    #pragma unroll
    for (int q = 0; q < 4; ++q) {
        float m = sm[q];
        #pragma unroll
        for (int off = 32; off > 0; off >>= 1) m += __shfl_down(m, off, 64);
        if ((tid & 63) == 0) red[q][tid >> 6] = m;
    }
    __syncthreads();
    if (tid < 4) {
        rowmax[i0 + tid] = mx[tid];
        rowsum[i0 + tid] = red[tid][0] + red[tid][1] + red[tid][2] + red[tid][3];
    }
}

__global__ __launch_bounds__(256) void col_sum_kernel(
    const float* __restrict__ nv1, const float* __restrict__ nv2,
    const float* __restrict__ rowmax, const float* __restrict__ rowsum,
    float* __restrict__ deg)
{
    const int j = blockIdx.x * 256 + threadIdx.x;
    const int i0 = blockIdx.y * 256;
    float v[R_RANK];
    #pragma unroll
    for (int r = 0; r < R_RANK; ++r) v[r] = nv2[r * NN + j];
    float acc = 0.f;
    for (int i = i0; i < i0 + 256; ++i) {
        float s = 0.f;
        #pragma unroll
        for (int r = 0; r < R_RANK; ++r) s = fmaf(nv1[i * R_RANK + r], v[r], s);
        s = fmaxf(s, 0.f);
        acc += __expf(s - rowmax[i]) * (1.0f / rowsum[i]);
    }
    atomicAdd(&deg[j], acc);
}

__global__ __launch_bounds__(256) void an_build_kernel(
    const float* __restrict__ nv1, const float* __restrict__ nv2,
    const float* __restrict__ rowmax, const float* __restrict__ rowsum,
    const float* __restrict__ deg, unsigned short* __restrict__ AnT)
{
    const int tid = threadIdx.x;
    const int j = blockIdx.x * 256 + tid;
    const int i0 = blockIdx.y * 8;
    __shared__ float v2s[8][R_RANK];
    __shared__ float dis[8];
    if (tid < 8 * R_RANK) {
        const int r = tid / 8, t = tid % 8;
        v2s[t][r] = nv2[r * NN + i0 + t];
    }
    if (tid < 8) dis[tid] = rsqrtf(1.0f + deg[i0 + tid]);

    float a[R_RANK];
    #pragma unroll
    for (int r = 0; r < R_RANK; ++r) a[r] = nv1[j * R_RANK + r];
    const float rm = rowmax[j];
    const float rs = 1.0f / rowsum[j];
    const float dj = rsqrtf(1.0f + deg[j]);
    __syncthreads();

    #pragma unroll
    for (int t = 0; t < 8; ++t) {
        const int i = i0 + t;
        float s = 0.f;
        #pragma unroll
        for (int r = 0; r < R_RANK; ++r) s = fmaf(a[r], v2s[t][r], s);
        s = fmaxf(s, 0.f);
        const float adp = __expf(s - rm) * rs;
        const float val = (adp + ((i == j) ? 1.f : 0.f)) * dis[t] * dj;
        AnT[(size_t)i * NN + j] = f2bf(val);
    }
}

// ---------------------------------------------------------------------------
// prep: z=0 w_map^T, z=1 w1^T, z=2 w2^T (fp32 -> bf16 transposed), z=3 cvt x
// ---------------------------------------------------------------------------
__global__ __launch_bounds__(256) void prep_kernel(
    const float* __restrict__ x, const float* __restrict__ w_map,
    const float* __restrict__ w1, const float* __restrict__ w2,
    unsigned short* __restrict__ xb, unsigned short* __restrict__ wmT,
    unsigned short* __restrict__ w1T, unsigned short* __restrict__ w2T)
{
    const int z = blockIdx.z;
    const int tid = threadIdx.x;
    if (z == 3) {
        const int b = blockIdx.x + blockIdx.y * 32;
        const size_t base = (size_t)b * 4096 + (size_t)tid * 16;
        #pragma unroll
        for (int i = 0; i < 2; ++i) {
            const float4 a0 = *(const float4*)(x + base + i * 8);
            const float4 a1 = *(const float4*)(x + base + i * 8 + 4);
            ushort4 p, q;
            p.x = f2bf(a0.x); p.y = f2bf(a0.y); p.z = f2bf(a0.z); p.w = f2bf(a0.w);
            q.x = f2bf(a1.x); q.y = f2bf(a1.y); q.z = f2bf(a1.z); q.w = f2bf(a1.w);
            *(ushort4*)(xb + base + i * 8) = p;
            *(ushort4*)(xb + base + i * 8 + 4) = q;
        }
        return;
    }
    const float* W = (z == 0) ? w_map : (z == 1) ? w1 : w2;
    unsigned short* WT = (z == 0) ? wmT : (z == 1) ? w1T : w2T;
    const int CN = (z == 2) ? 512 : 1024;
    if (blockIdx.x * 32 >= CN) return;
    __shared__ float s[32][33];
    const int tx = tid & 31, ty = tid >> 5;
    const int r0 = blockIdx.y * 32, c0 = blockIdx.x * 32;
    #pragma unroll
    for (int i = 0; i < 4; ++i)
        s[ty + 8 * i][tx] = W[(size_t)(r0 + ty + 8 * i) * CN + c0 + tx];
    __syncthreads();
    #pragma unroll
    for (int i = 0; i < 4; ++i)
        WT[(size_t)(c0 + ty + 8 * i) * 1024 + r0 + tx] = f2bf(s[tx][ty + 8 * i]);
}

// ---------------------------------------------------------------------------
// bf16 MFMA GEMM (R3-verified): 128x128 tile, BK=32, 4 waves (2x2), 4x4 frags,
// frag-ordered conflict-free LDS. Split-K partials: TRANS=0 P[z][M][N],
// TRANS=1 P[z][N][M] (contiguous floatx4 stores).
// ---------------------------------------------------------------------------
template<int TRANS, int SK>
__global__ __launch_bounds__(256) void gemm_mfma(
    const unsigned short* __restrict__ A, const unsigned short* __restrict__ Bt,
    float* __restrict__ P, const int M, const int N, const int K)
{
    __shared__ __align__(16) unsigned short As[4096];  // 8 chunks x 1KB, frag-ordered
    __shared__ __align__(16) unsigned short Bs[4096];
    const int tid = threadIdx.x;
    const int l = tid & 63, w = tid >> 6;
    const int wy = w >> 1, wx = w & 1;
    const int row0 = blockIdx.y * 128, col0 = blockIdx.x * 128;
    const int Kc = K / SK;
    const int kb = blockIdx.z * Kc;
    const int lr = l & 15, lq = l >> 4;

    // wave w stages chunks 2w, 2w+1. Chunk c lane p holds row c*16+(p&15),
    // k-quad p>>4 -> LDS is exact fragment order.
    const unsigned short* Ag0 = A + (size_t)(row0 + 2 * w * 16 + lr) * K + kb + lq * 8;
    const unsigned short* Ag1 = Ag0 + (size_t)16 * K;
    const unsigned short* Bg0 = Bt + (size_t)(col0 + 2 * w * 16 + lr) * K + kb + lq * 8;
    const unsigned short* Bg1 = Bg0 + (size_t)16 * K;
    char* Asw0 = (char*)As + 2 * w * 1024;
    char* Bsw0 = (char*)Bs + 2 * w * 1024;

    floatx4 acc[4][4];
    #pragma unroll
    for (int i = 0; i < 4; ++i)
        #pragma unroll
        for (int j = 0; j < 4; ++j) acc[i][j] = (floatx4){0.f, 0.f, 0.f, 0.f};

    const char* Afr = (const char*)As + wy * 4096 + l * 16;
    const char* Bfr = (const char*)Bs + wx * 4096 + l * 16;

    for (int k0 = 0; k0 < Kc; k0 += 32) {
        __syncthreads();                    // WAR on LDS
        gll16(Ag0 + k0, Asw0);
        gll16(Ag1 + k0, Asw0 + 1024);
        gll16(Bg0 + k0, Bsw0);
        gll16(Bg1 + k0, Bsw0 + 1024);
        __syncthreads();                    // drains vmcnt: tile ready

        bf16x8 af[4], bf[4];
        #pragma unroll
        for (int i = 0; i < 4; ++i) af[i] = *(const bf16x8*)(Afr + i * 1024);
        #pragma unroll
        for (int i = 0; i < 4; ++i) bf[i] = *(const bf16x8*)(Bfr + i * 1024);
        #pragma unroll
        for (int mf = 0; mf < 4; ++mf)
            #pragma unroll
            for (int nf = 0; nf < 4; ++nf)
                acc[mf][nf] = __builtin_amdgcn_mfma_f32_16x16x32_bf16(
                    af[mf], bf[nf], acc[mf][nf], 0, 0, 0);
    }

    float* Pz = P + (size_t)blockIdx.z * M * N;
    const int gr0 = row0 + wy * 64 + lq * 4;
    const int gc0 = col0 + wx * 64 + lr;
    #pragma unroll
    for (int mf = 0; mf < 4; ++mf) {
        const int gr = gr0 + mf * 16;
        #pragma unroll
        for (int nf = 0; nf < 4; ++nf) {
            const int gc = gc0 + nf * 16;
            if constexpr (TRANS == 0) {
                #pragma unroll
                for (int r = 0; r < 4; ++r)
                    Pz[(size_t)(gr + r) * N + gc] = acc[mf][nf][r];
            } else {
                *(floatx4*)&Pz[(size_t)gc * M + gr] = acc[mf][nf];  // 16B aligned
            }
        }
    }
}

// ---------------------------------------------------------------------------
// Split-K reduce + epilogue -> bf16. EPI: 0 none, 1 relu(x+b), 2 bn(relu(x+b)).
// IDXM: 0 = params indexed by column (i % NC).
// ---------------------------------------------------------------------------
template<int EPI, int S, int NC>
__global__ __launch_bounds__(256) void reduce_k(
    const float* __restrict__ P, unsigned short* __restrict__ out, const int MN,
    const float* __restrict__ bias, const float* __restrict__ gamma,
    const float* __restrict__ beta, const float* __restrict__ mean,
    const float* __restrict__ var)
{
    const int idx = blockIdx.x * 256 + threadIdx.x;   // float4 index
    const int n4 = MN >> 2;
    const float4* Pv = (const float4*)P;
    float4 v = Pv[idx];
    #pragma unroll
    for (int z = 1; z < S; ++z) {
        const float4 t = Pv[idx + (size_t)z * n4];
        v.x += t.x; v.y += t.y; v.z += t.z; v.w += t.w;
    }
    float vals[4] = {v.x, v.y, v.z, v.w};
    if constexpr (EPI >= 1) {
        const int c0 = (idx << 2) & (NC - 1);
        const float4 b4 = *(const float4*)(bias + c0);
        const float bb[4] = {b4.x, b4.y, b4.z, b4.w};
        float sc[4], sh[4];
        if constexpr (EPI == 2) {
            const float4 g4 = *(const float4*)(gamma + c0);
            const float4 e4 = *(const float4*)(beta + c0);
            const float4 m4 = *(const float4*)(mean + c0);
            const float4 v4 = *(const float4*)(var + c0);
            const float gg[4] = {g4.x, g4.y, g4.z, g4.w};
            const float ee[4] = {e4.x, e4.y, e4.z, e4.w};
            const float mm[4] = {m4.x, m4.y, m4.z, m4.w};
            const float vv[4] = {v4.x, v4.y, v4.z, v4.w};
            #pragma unroll
            for (int j = 0; j < 4; ++j) {
                sc[j] = gg[j] * rsqrtf(vv[j] + 1e-5f);
                sh[j] = ee[j] - mm[j] * sc[j];
            }
        }
        #pragma unroll
        for (int j = 0; j < 4; ++j) {
            float xv = fmaxf(vals[j] + bb[j], 0.f);
            if constexpr (EPI == 2) xv = fmaf(xv, sc[j], sh[j]);
            vals[j] = xv;
        }
    }
    ushort4 p;
    p.x = f2bf(vals[0]); p.y = f2bf(vals[1]); p.z = f2bf(vals[2]); p.w = f2bf(vals[3]);
    *(ushort4*)(out + ((size_t)idx << 2)) = p;
}

// ---------------------------------------------------------------------------
// Split-K reduce + bn2(relu(x+b)) + mean-pool (h2 never materialized).
// P[z][512][4096]; params row(=channel)-indexed; atomicAdd per-block sums.
// ---------------------------------------------------------------------------
template<int S>
__global__ __launch_bounds__(256) void reduce_pool_kernel(
    const float* __restrict__ P, float* __restrict__ pooled,
    const float* __restrict__ bias, const float* __restrict__ gamma,
    const float* __restrict__ beta, const float* __restrict__ mean,
    const float* __restrict__ var)
{
    const int idx = blockIdx.x * 256 + threadIdx.x;   // float4 index
    const int row = blockIdx.x >> 2;                  // 4096 floats = 1024 f4 per row
    constexpr int n4 = 512 * 4096 / 4;
    const float4* Pv = (const float4*)P;
    float4 v = Pv[idx];
    #pragma unroll
    for (int z = 1; z < S; ++z) {
        const float4 t = Pv[idx + (size_t)z * n4];
        v.x += t.x; v.y += t.y; v.z += t.z; v.w += t.w;
    }
    const float b0 = bias[row];
    const float sc = gamma[row] * rsqrtf(var[row] + 1e-5f);
    const float sh = beta[row] - mean[row] * sc;
    float s = 0.f;
    const float vals[4] = {v.x, v.y, v.z, v.w};
    #pragma unroll
    for (int j = 0; j < 4; ++j)
        s += fmaf(fmaxf(vals[j] + b0, 0.f), sc, sh);
    #pragma unroll
    for (int off = 32; off > 0; off >>= 1) s += __shfl_down(s, off, 64);
    __shared__ float red[4];
    if ((threadIdx.x & 63) == 0) red[threadIdx.x >> 6] = s;
    __syncthreads();
    if (threadIdx.x == 0)
        atomicAdd(&pooled[row], red[0] + red[1] + red[2] + red[3]);
}

__global__ __launch_bounds__(512) void finalize_kernel(
    const float* __restrict__ pooled, const float* __restrict__ w_attn,
    const float* __restrict__ b_attn, float* __restrict__ out)
{
    const int c = threadIdx.x;
    __shared__ float red[512];
    const float p = pooled[c] * (1.0f / 4096.0f);
    red[c] = p * w_attn[c];
    __syncthreads();
    for (int s = 256; s > 0; s >>= 1) {
        if (c < s) red[c] += red[c + s];
        __syncthreads();
    }
    const float attn = 1.0f / (1.0f + __expf(-(red[0] + b_attn[0])));
    out[c] = p * attn;
}

// ---------------------------------------------------------------------------
extern "C" void kernel_launch(void* const* d_in, const int* in_sizes, int n_in,
                              void* d_out, int out_size, void* d_ws, size_t ws_size,
                              hipStream_t stream) {
    const float* x      = (const float*)d_in[0];
    const float* w_map  = (const float*)d_in[1];
    const float* b_map  = (const float*)d_in[2];
    const float* nv1    = (const float*)d_in[3];
    const float* nv2    = (const float*)d_in[4];
    const float* w1     = (const float*)d_in[5];
    const float* b1     = (const float*)d_in[6];
    const float* w2     = (const float*)d_in[7];
    const float* b2     = (const float*)d_in[8];
    const float* bn1_g  = (const float*)d_in[9];
    const float* bn1_b  = (const float*)d_in[10];
    const float* bn1_m  = (const float*)d_in[11];
    const float* bn1_v  = (const float*)d_in[12];
    const float* bn2_g  = (const float*)d_in[13];
    const float* bn2_b  = (const float*)d_in[14];
    const float* bn2_m  = (const float*)d_in[15];
    const float* bn2_v  = (const float*)d_in[16];
    const float* w_attn = (const float*)d_in[17];
    const float* b_attn = (const float*)d_in[18];
    float* out = (float*)d_out;

    // ws_size is constant across calls -> branch is graph-capture safe.
    const bool big = ws_size >= (size_t)124 * 1024 * 1024;   // need 117.1 MB
    const size_t MB = 1024 * 1024;
    char* ws = (char*)d_ws;
    unsigned short* AnT = (unsigned short*)(ws);                  // [0,32M)
    float*          P   = (float*)(ws + 32 * MB);                 // 64 MB (big) / 32 MB
    char* B0 = ws + (big ? 96 * MB : 64 * MB);
    unsigned short* xb  = (unsigned short*)(B0);                  // 8 MB, dead after G1
    unsigned short* t1T = (unsigned short*)(B0);                  //   reuse, dead after G3
    unsigned short* t2T = (unsigned short*)(B0);                  //   reuse after G3
    unsigned short* xm  = (unsigned short*)(B0 + 8 * MB);         // 8 MB, dead after G2
    unsigned short* h1  = (unsigned short*)(B0 + 8 * MB);         //   reuse, dead after G4
    unsigned short* wmT = (unsigned short*)(B0 + 16 * MB);        // 2 MB
    unsigned short* w1T = (unsigned short*)(B0 + 18 * MB);        // 2 MB
    unsigned short* w2T = (unsigned short*)(B0 + 20 * MB);        // 1 MB
    float* deg    = (float*)(B0 + 21 * MB);
    float* rowmax = deg + 4096;
    float* rowsum = rowmax + 4096;
    float* pooled = rowsum + 4096;

    // prep + adjacency (4 nodes)
    prep_kernel<<<dim3(32, 32, 4), 256, 0, stream>>>(x, w_map, w1, w2, xb, wmT, w1T, w2T);
    row_stats_kernel<<<1024, 256, 0, stream>>>(nv1, nv2, rowmax, rowsum, deg, pooled);
    col_sum_kernel<<<dim3(16, 16), 256, 0, stream>>>(nv1, nv2, rowmax, rowsum, deg);
    an_build_kernel<<<dim3(16, 512), 256, 0, stream>>>(nv1, nv2, rowmax, rowsum, deg, AnT);

    // G1: xm = relu(x @ w_map + b)   M4096 N1024 K1024, SK2 (512 blocks)
    gemm_mfma<0, 2><<<dim3(8, 32, 2), 256, 0, stream>>>(xb, wmT, P, 4096, 1024, 1024);
    reduce_k<1, 2, 1024><<<4096, 256, 0, stream>>>(P, xm, 4194304,
        b_map, nullptr, nullptr, nullptr, nullptr);
    // G2: t1T = (xm @ w1)^T          SK2, transposed partials
    gemm_mfma<1, 2><<<dim3(8, 32, 2), 256, 0, stream>>>(xm, w1T, P, 4096, 1024, 1024);
    reduce_k<0, 2, 1><<<4096, 256, 0, stream>>>(P, t1T, 4194304,
        nullptr, nullptr, nullptr, nullptr, nullptr);
    // G3: h1 = bn1(relu(AnT @ t1 + b1))  M4096 N1024 K4096, SK4 big (1024 blk)
    if (big) {
        gemm_mfma<0, 4><<<dim3(8, 32, 4), 256, 0, stream>>>(AnT, t1T, P, 4096, 1024, 4096);
        reduce_k<2, 4, 1024><<<4096, 256, 0, stream>>>(P, h1, 4194304,
            b1, bn1_g, bn1_b, bn1_m, bn1_v);
    } else {
        gemm_mfma<0, 2><<<dim3(8, 32, 2), 256, 0, stream>>>(AnT, t1T, P, 4096, 1024, 4096);
        reduce_k<2, 2, 1024><<<4096, 256, 0, stream>>>(P, h1, 4194304,
            b1, bn1_g, bn1_b, bn1_m, bn1_v);
    }
    // G4 (swapped): t2T = w2T @ h1^T   M512 N4096 K1024, SK2 (256 blocks)
    gemm_mfma<0, 2><<<dim3(32, 4, 2), 256, 0, stream>>>(w2T, h1, P, 512, 4096, 1024);
    reduce_k<0, 2, 1><<<2048, 256, 0, stream>>>(P, t2T, 2097152,
        nullptr, nullptr, nullptr, nullptr, nullptr);
    // G5 (swapped): t2T @ AnT^T   M512 N4096 K4096, SK8 big (1024 blocks)
    if (big) {
        gemm_mfma<0, 8><<<dim3(32, 4, 8), 256, 0, stream>>>(t2T, AnT, P, 512, 4096, 4096);
        reduce_pool_kernel<8><<<2048, 256, 0, stream>>>(
            P, pooled, b2, bn2_g, bn2_b, bn2_m, bn2_v);
    } else {
        gemm_mfma<0, 4><<<dim3(32, 4, 4), 256, 0, stream>>>(t2T, AnT, P, 512, 4096, 4096);
        reduce_pool_kernel<4><<<2048, 256, 0, stream>>>(
            P, pooled, b2, bn2_g, bn2_b, bn2_m, bn2_v);
    }

    finalize_kernel<<<1, 512, 0, stream>>>(pooled, w_attn, b_attn, out);
}

// Round 6
// 395.173 us; speedup vs baseline: 1.1062x; 1.1062x over previous
//
#include <hip/hip_runtime.h>

#define NN 4096
#define R_RANK 10

typedef __bf16 bf16x8 __attribute__((ext_vector_type(8)));
typedef float floatx4 __attribute__((ext_vector_type(4)));

__device__ __forceinline__ unsigned short f2bf(float f) {
    union { float f; unsigned int u; } v; v.f = f;
    unsigned int r = v.u + 0x7FFFu + ((v.u >> 16) & 1u);   // RNE
    return (unsigned short)(r >> 16);
}
// async global->LDS, 16B per lane; LDS dest = wave-uniform base + lane*16
__device__ __forceinline__ void gll16(const void* g, void* l) {
    __builtin_amdgcn_global_load_lds(
        (const __attribute__((address_space(1))) unsigned int*)g,
        (__attribute__((address_space(3))) unsigned int*)l, 16, 0, 0);
}

// ---------------------------------------------------------------------------
// Adjacency: row stats (4 rows/block; zeroes deg+pooled) -> col degree -> AnT
// ---------------------------------------------------------------------------
__global__ __launch_bounds__(256) void row_stats_kernel(
    const float* __restrict__ nv1, const float* __restrict__ nv2,
    float* __restrict__ rowmax, float* __restrict__ rowsum,
    float* __restrict__ deg, float* __restrict__ pooled)
{
    const int i0 = blockIdx.x * 4;
    const int tid = threadIdx.x;
    if (blockIdx.x < 16) deg[blockIdx.x * 256 + tid] = 0.f;
    if (blockIdx.x >= 16 && blockIdx.x < 18) pooled[(blockIdx.x - 16) * 256 + tid] = 0.f;
    __shared__ float a[4][R_RANK];
    if (tid < 4 * R_RANK) a[tid / R_RANK][tid % R_RANK] = nv1[i0 * R_RANK + tid];
    __syncthreads();

    float s[4][16];
    float mx[4] = {0.f, 0.f, 0.f, 0.f};   // relu >= 0
    #pragma unroll
    for (int t = 0; t < 16; ++t) {
        const int j = t * 256 + tid;
        float v[R_RANK];
        #pragma unroll
        for (int r = 0; r < R_RANK; ++r) v[r] = nv2[r * NN + j];
        #pragma unroll
        for (int q = 0; q < 4; ++q) {
            float acc = 0.f;
            #pragma unroll
            for (int r = 0; r < R_RANK; ++r) acc = fmaf(a[q][r], v[r], acc);
            acc = fmaxf(acc, 0.f);
            s[q][t] = acc;
            mx[q] = fmaxf(mx[q], acc);
        }
    }
    __shared__ float red[4][4];
    #pragma unroll
    for (int q = 0; q < 4; ++q) {
        float m = mx[q];
        #pragma unroll
        for (int off = 32; off > 0; off >>= 1) m = fmaxf(m, __shfl_down(m, off, 64));
        if ((tid & 63) == 0) red[q][tid >> 6] = m;
    }
    __syncthreads();
    #pragma unroll
    for (int q = 0; q < 4; ++q)
        mx[q] = fmaxf(fmaxf(red[q][0], red[q][1]), fmaxf(red[q][2], red[q][3]));
    __syncthreads();
    float sm[4] = {0.f, 0.f, 0.f, 0.f};
    #pragma unroll
    for (int t = 0; t < 16; ++t)
        #pragma unroll
        for (int q = 0; q < 4; ++q) sm[q] += __expf(s[q][t] - mx[q]);
    #pragma unroll
    for (int q = 0; q < 4; ++q) {
        float m = sm[q];
        #pragma unroll
        for (int off = 32; off > 0; off >>= 1) m += __shfl_down(m, off, 64);
        if ((tid & 63) == 0) red[q][tid >> 6] = m;
    }
    __syncthreads();
    if (tid < 4) {
        rowmax[i0 + tid] = mx[tid];
        rowsum[i0 + tid] = red[tid][0] + red[tid][1] + red[tid][2] + red[tid][3];
    }
}

__global__ __launch_bounds__(256) void col_sum_kernel(
    const float* __restrict__ nv1, const float* __restrict__ nv2,
    const float* __restrict__ rowmax, const float* __restrict__ rowsum,
    float* __restrict__ deg)
{
    const int j = blockIdx.x * 256 + threadIdx.x;
    const int i0 = blockIdx.y * 256;
    float v[R_RANK];
    #pragma unroll
    for (int r = 0; r < R_RANK; ++r) v[r] = nv2[r * NN + j];
    float acc = 0.f;
    for (int i = i0; i < i0 + 256; ++i) {
        float s = 0.f;
        #pragma unroll
        for (int r = 0; r < R_RANK; ++r) s = fmaf(nv1[i * R_RANK + r], v[r], s);
        s = fmaxf(s, 0.f);
        acc += __expf(s - rowmax[i]) * (1.0f / rowsum[i]);
    }
    atomicAdd(&deg[j], acc);
}

__global__ __launch_bounds__(256) void an_build_kernel(
    const float* __restrict__ nv1, const float* __restrict__ nv2,
    const float* __restrict__ rowmax, const float* __restrict__ rowsum,
    const float* __restrict__ deg, unsigned short* __restrict__ AnT)
{
    const int tid = threadIdx.x;
    const int j = blockIdx.x * 256 + tid;
    const int i0 = blockIdx.y * 8;
    __shared__ float v2s[8][R_RANK];
    __shared__ float dis[8];
    if (tid < 8 * R_RANK) {
        const int r = tid / 8, t = tid % 8;
        v2s[t][r] = nv2[r * NN + i0 + t];
    }
    if (tid < 8) dis[tid] = rsqrtf(1.0f + deg[i0 + tid]);

    float a[R_RANK];
    #pragma unroll
    for (int r = 0; r < R_RANK; ++r) a[r] = nv1[j * R_RANK + r];
    const float rm = rowmax[j];
    const float rs = 1.0f / rowsum[j];
    const float dj = rsqrtf(1.0f + deg[j]);
    __syncthreads();

    #pragma unroll
    for (int t = 0; t < 8; ++t) {
        const int i = i0 + t;
        float s = 0.f;
        #pragma unroll
        for (int r = 0; r < R_RANK; ++r) s = fmaf(a[r], v2s[t][r], s);
        s = fmaxf(s, 0.f);
        const float adp = __expf(s - rm) * rs;
        const float val = (adp + ((i == j) ? 1.f : 0.f)) * dis[t] * dj;
        AnT[(size_t)i * NN + j] = f2bf(val);
    }
}

// ---------------------------------------------------------------------------
// prep: z=0 w_map^T, z=1 w1^T, z=2 w2^T (fp32 -> bf16 transposed), z=3 cvt x
// ---------------------------------------------------------------------------
__global__ __launch_bounds__(256) void prep_kernel(
    const float* __restrict__ x, const float* __restrict__ w_map,
    const float* __restrict__ w1, const float* __restrict__ w2,
    unsigned short* __restrict__ xb, unsigned short* __restrict__ wmT,
    unsigned short* __restrict__ w1T, unsigned short* __restrict__ w2T)
{
    const int z = blockIdx.z;
    const int tid = threadIdx.x;
    if (z == 3) {
        const int b = blockIdx.x + blockIdx.y * 32;
        const size_t base = (size_t)b * 4096 + (size_t)tid * 16;
        #pragma unroll
        for (int i = 0; i < 2; ++i) {
            const float4 a0 = *(const float4*)(x + base + i * 8);
            const float4 a1 = *(const float4*)(x + base + i * 8 + 4);
            ushort4 p, q;
            p.x = f2bf(a0.x); p.y = f2bf(a0.y); p.z = f2bf(a0.z); p.w = f2bf(a0.w);
            q.x = f2bf(a1.x); q.y = f2bf(a1.y); q.z = f2bf(a1.z); q.w = f2bf(a1.w);
            *(ushort4*)(xb + base + i * 8) = p;
            *(ushort4*)(xb + base + i * 8 + 4) = q;
        }
        return;
    }
    const float* W = (z == 0) ? w_map : (z == 1) ? w1 : w2;
    unsigned short* WT = (z == 0) ? wmT : (z == 1) ? w1T : w2T;
    const int CN = (z == 2) ? 512 : 1024;
    if (blockIdx.x * 32 >= CN) return;
    __shared__ float s[32][33];
    const int tx = tid & 31, ty = tid >> 5;
    const int r0 = blockIdx.y * 32, c0 = blockIdx.x * 32;
    #pragma unroll
    for (int i = 0; i < 4; ++i)
        s[ty + 8 * i][tx] = W[(size_t)(r0 + ty + 8 * i) * CN + c0 + tx];
    __syncthreads();
    #pragma unroll
    for (int i = 0; i < 4; ++i)
        WT[(size_t)(c0 + ty + 8 * i) * 1024 + r0 + tx] = f2bf(s[tx][ty + 8 * i]);
}

// ---------------------------------------------------------------------------
// bf16 MFMA GEMM: 128x128 tile, BK=64 (two 8KB half-tiles), 4 waves (2x2),
// 4x4 frags, frag-ordered conflict-free LDS, 32 MFMA per barrier-pair.
// Split-K partials: TRANS=0 P[z][M][N], TRANS=1 P[z][N][M].
// ---------------------------------------------------------------------------
template<int TRANS, int SK>
__global__ __launch_bounds__(256) void gemm_mfma(
    const unsigned short* __restrict__ A, const unsigned short* __restrict__ Bt,
    float* __restrict__ P, const int M, const int N, const int K)
{
    // [half k0/k32][8 chunks][512 elems]; 16 KB each
    __shared__ __align__(16) unsigned short As[8192];
    __shared__ __align__(16) unsigned short Bs[8192];
    const int tid = threadIdx.x;
    const int l = tid & 63, w = tid >> 6;
    const int wy = w >> 1, wx = w & 1;
    const int row0 = blockIdx.y * 128, col0 = blockIdx.x * 128;
    const int Kc = K / SK;
    const int kb = blockIdx.z * Kc;
    const int lr = l & 15, lq = l >> 4;

    // wave w stages chunks 2w, 2w+1 of each half. Chunk c lane p holds
    // row c*16+(p&15), k-quad p>>4 -> LDS is exact fragment order.
    const unsigned short* Ag0 = A + (size_t)(row0 + 2 * w * 16 + lr) * K + kb + lq * 8;
    const unsigned short* Ag1 = Ag0 + (size_t)16 * K;
    const unsigned short* Bg0 = Bt + (size_t)(col0 + 2 * w * 16 + lr) * K + kb + lq * 8;
    const unsigned short* Bg1 = Bg0 + (size_t)16 * K;
    char* Asw = (char*)As + 2 * w * 1024;
    char* Bsw = (char*)Bs + 2 * w * 1024;

    floatx4 acc[4][4];
    #pragma unroll
    for (int i = 0; i < 4; ++i)
        #pragma unroll
        for (int j = 0; j < 4; ++j) acc[i][j] = (floatx4){0.f, 0.f, 0.f, 0.f};

    const char* Afr = (const char*)As + wy * 4096 + l * 16;
    const char* Bfr = (const char*)Bs + wx * 4096 + l * 16;

    for (int k0 = 0; k0 < Kc; k0 += 64) {
        __syncthreads();                    // WAR on LDS
        #pragma unroll
        for (int h = 0; h < 2; ++h) {       // half h covers k in [h*32, h*32+32)
            gll16(Ag0 + k0 + h * 32, Asw + h * 8192);
            gll16(Ag1 + k0 + h * 32, Asw + h * 8192 + 1024);
            gll16(Bg0 + k0 + h * 32, Bsw + h * 8192);
            gll16(Bg1 + k0 + h * 32, Bsw + h * 8192 + 1024);
        }
        __syncthreads();                    // drains vmcnt: both halves ready

        #pragma unroll
        for (int h = 0; h < 2; ++h) {
            bf16x8 af[4], bf[4];
            #pragma unroll
            for (int i = 0; i < 4; ++i) af[i] = *(const bf16x8*)(Afr + h * 8192 + i * 1024);
            #pragma unroll
            for (int i = 0; i < 4; ++i) bf[i] = *(const bf16x8*)(Bfr + h * 8192 + i * 1024);
            #pragma unroll
            for (int mf = 0; mf < 4; ++mf)
                #pragma unroll
                for (int nf = 0; nf < 4; ++nf)
                    acc[mf][nf] = __builtin_amdgcn_mfma_f32_16x16x32_bf16(
                        af[mf], bf[nf], acc[mf][nf], 0, 0, 0);
        }
    }

    float* Pz = P + (size_t)blockIdx.z * M * N;
    const int gr0 = row0 + wy * 64 + lq * 4;
    const int gc0 = col0 + wx * 64 + lr;
    #pragma unroll
    for (int mf = 0; mf < 4; ++mf) {
        const int gr = gr0 + mf * 16;
        #pragma unroll
        for (int nf = 0; nf < 4; ++nf) {
            const int gc = gc0 + nf * 16;
            if constexpr (TRANS == 0) {
                #pragma unroll
                for (int r = 0; r < 4; ++r)
                    Pz[(size_t)(gr + r) * N + gc] = acc[mf][nf][r];
            } else {
                *(floatx4*)&Pz[(size_t)gc * M + gr] = acc[mf][nf];  // 16B aligned
            }
        }
    }
}

// ---------------------------------------------------------------------------
// Split-K reduce + epilogue -> bf16. EPI: 0 none, 1 relu(x+b), 2 bn(relu(x+b)).
// Params indexed by column (i % NC).
// ---------------------------------------------------------------------------
template<int EPI, int S, int NC>
__global__ __launch_bounds__(256) void reduce_k(
    const float* __restrict__ P, unsigned short* __restrict__ out, const int MN,
    const float* __restrict__ bias, const float* __restrict__ gamma,
    const float* __restrict__ beta, const float* __restrict__ mean,
    const float* __restrict__ var)
{
    const int idx = blockIdx.x * 256 + threadIdx.x;   // float4 index
    const int n4 = MN >> 2;
    const float4* Pv = (const float4*)P;
    float4 v = Pv[idx];
    #pragma unroll
    for (int z = 1; z < S; ++z) {
        const float4 t = Pv[idx + (size_t)z * n4];
        v.x += t.x; v.y += t.y; v.z += t.z; v.w += t.w;
    }
    float vals[4] = {v.x, v.y, v.z, v.w};
    if constexpr (EPI >= 1) {
        const int c0 = (idx << 2) & (NC - 1);
        const float4 b4 = *(const float4*)(bias + c0);
        const float bb[4] = {b4.x, b4.y, b4.z, b4.w};
        float sc[4], sh[4];
        if constexpr (EPI == 2) {
            const float4 g4 = *(const float4*)(gamma + c0);
            const float4 e4 = *(const float4*)(beta + c0);
            const float4 m4 = *(const float4*)(mean + c0);
            const float4 v4 = *(const float4*)(var + c0);
            const float gg[4] = {g4.x, g4.y, g4.z, g4.w};
            const float ee[4] = {e4.x, e4.y, e4.z, e4.w};
            const float mm[4] = {m4.x, m4.y, m4.z, m4.w};
            const float vv[4] = {v4.x, v4.y, v4.z, v4.w};
            #pragma unroll
            for (int j = 0; j < 4; ++j) {
                sc[j] = gg[j] * rsqrtf(vv[j] + 1e-5f);
                sh[j] = ee[j] - mm[j] * sc[j];
            }
        }
        #pragma unroll
        for (int j = 0; j < 4; ++j) {
            float xv = fmaxf(vals[j] + bb[j], 0.f);
            if constexpr (EPI == 2) xv = fmaf(xv, sc[j], sh[j]);
            vals[j] = xv;
        }
    }
    ushort4 p;
    p.x = f2bf(vals[0]); p.y = f2bf(vals[1]); p.z = f2bf(vals[2]); p.w = f2bf(vals[3]);
    *(ushort4*)(out + ((size_t)idx << 2)) = p;
}

// ---------------------------------------------------------------------------
// Split-K reduce + bn2(relu(x+b)) + mean-pool (h2 never materialized).
// P[z][512][4096]; params row(=channel)-indexed; atomicAdd per-block sums.
// ---------------------------------------------------------------------------
template<int S>
__global__ __launch_bounds__(256) void reduce_pool_kernel(
    const float* __restrict__ P, float* __restrict__ pooled,
    const float* __restrict__ bias, const float* __restrict__ gamma,
    const float* __restrict__ beta, const float* __restrict__ mean,
    const float* __restrict__ var)
{
    const int idx = blockIdx.x * 256 + threadIdx.x;   // float4 index
    const int row = blockIdx.x >> 2;                  // 4096 floats = 1024 f4 per row
    constexpr int n4 = 512 * 4096 / 4;
    const float4* Pv = (const float4*)P;
    float4 v = Pv[idx];
    #pragma unroll
    for (int z = 1; z < S; ++z) {
        const float4 t = Pv[idx + (size_t)z * n4];
        v.x += t.x; v.y += t.y; v.z += t.z; v.w += t.w;
    }
    const float b0 = bias[row];
    const float sc = gamma[row] * rsqrtf(var[row] + 1e-5f);
    const float sh = beta[row] - mean[row] * sc;
    float s = 0.f;
    const float vals[4] = {v.x, v.y, v.z, v.w};
    #pragma unroll
    for (int j = 0; j < 4; ++j)
        s += fmaf(fmaxf(vals[j] + b0, 0.f), sc, sh);
    #pragma unroll
    for (int off = 32; off > 0; off >>= 1) s += __shfl_down(s, off, 64);
    __shared__ float red[4];
    if ((threadIdx.x & 63) == 0) red[threadIdx.x >> 6] = s;
    __syncthreads();
    if (threadIdx.x == 0)
        atomicAdd(&pooled[row], red[0] + red[1] + red[2] + red[3]);
}

__global__ __launch_bounds__(512) void finalize_kernel(
    const float* __restrict__ pooled, const float* __restrict__ w_attn,
    const float* __restrict__ b_attn, float* __restrict__ out)
{
    const int c = threadIdx.x;
    __shared__ float red[512];
    const float p = pooled[c] * (1.0f / 4096.0f);
    red[c] = p * w_attn[c];
    __syncthreads();
    for (int s = 256; s > 0; s >>= 1) {
        if (c < s) red[c] += red[c + s];
        __syncthreads();
    }
    const float attn = 1.0f / (1.0f + __expf(-(red[0] + b_attn[0])));
    out[c] = p * attn;
}

// ---------------------------------------------------------------------------
extern "C" void kernel_launch(void* const* d_in, const int* in_sizes, int n_in,
                              void* d_out, int out_size, void* d_ws, size_t ws_size,
                              hipStream_t stream) {
    const float* x      = (const float*)d_in[0];
    const float* w_map  = (const float*)d_in[1];
    const float* b_map  = (const float*)d_in[2];
    const float* nv1    = (const float*)d_in[3];
    const float* nv2    = (const float*)d_in[4];
    const float* w1     = (const float*)d_in[5];
    const float* b1     = (const float*)d_in[6];
    const float* w2     = (const float*)d_in[7];
    const float* b2     = (const float*)d_in[8];
    const float* bn1_g  = (const float*)d_in[9];
    const float* bn1_b  = (const float*)d_in[10];
    const float* bn1_m  = (const float*)d_in[11];
    const float* bn1_v  = (const float*)d_in[12];
    const float* bn2_g  = (const float*)d_in[13];
    const float* bn2_b  = (const float*)d_in[14];
    const float* bn2_m  = (const float*)d_in[15];
    const float* bn2_v  = (const float*)d_in[16];
    const float* w_attn = (const float*)d_in[17];
    const float* b_attn = (const float*)d_in[18];
    float* out = (float*)d_out;

    // workspace (~85.1 MB), aliasing lifetime-checked:
    const size_t MB = 1024 * 1024;
    char* ws = (char*)d_ws;
    unsigned short* AnT = (unsigned short*)(ws);                  // [0,32M)
    float*          P   = (float*)(ws + 32 * MB);                 // [32M,64M) partials
    char* B0 = ws + 64 * MB;
    unsigned short* xb  = (unsigned short*)(B0);                  // 8 MB, dead after G1
    unsigned short* t1T = (unsigned short*)(B0);                  //   reuse, dead after G3
    unsigned short* t2T = (unsigned short*)(B0);                  //   reuse after G3
    unsigned short* xm  = (unsigned short*)(B0 + 8 * MB);         // 8 MB, dead after G2
    unsigned short* h1  = (unsigned short*)(B0 + 8 * MB);         //   reuse, dead after G4
    unsigned short* wmT = (unsigned short*)(B0 + 16 * MB);        // 2 MB
    unsigned short* w1T = (unsigned short*)(B0 + 18 * MB);        // 2 MB
    unsigned short* w2T = (unsigned short*)(B0 + 20 * MB);        // 1 MB
    float* deg    = (float*)(B0 + 21 * MB);
    float* rowmax = deg + 4096;
    float* rowsum = rowmax + 4096;
    float* pooled = rowsum + 4096;

    // prep + adjacency (4 nodes)
    prep_kernel<<<dim3(32, 32, 4), 256, 0, stream>>>(x, w_map, w1, w2, xb, wmT, w1T, w2T);
    row_stats_kernel<<<1024, 256, 0, stream>>>(nv1, nv2, rowmax, rowsum, deg, pooled);
    col_sum_kernel<<<dim3(16, 16), 256, 0, stream>>>(nv1, nv2, rowmax, rowsum, deg);
    an_build_kernel<<<dim3(16, 512), 256, 0, stream>>>(nv1, nv2, rowmax, rowsum, deg, AnT);

    // G1: xm = relu(x @ w_map + b)   M4096 N1024 K1024, SK2 (512 blocks)
    gemm_mfma<0, 2><<<dim3(8, 32, 2), 256, 0, stream>>>(xb, wmT, P, 4096, 1024, 1024);
    reduce_k<1, 2, 1024><<<4096, 256, 0, stream>>>(P, xm, 4194304,
        b_map, nullptr, nullptr, nullptr, nullptr);
    // G2: t1T = (xm @ w1)^T          SK2, transposed partials
    gemm_mfma<1, 2><<<dim3(8, 32, 2), 256, 0, stream>>>(xm, w1T, P, 4096, 1024, 1024);
    reduce_k<0, 2, 1><<<4096, 256, 0, stream>>>(P, t1T, 4194304,
        nullptr, nullptr, nullptr, nullptr, nullptr);
    // G3: h1 = bn1(relu(AnT @ t1 + b1))  M4096 N1024 K4096, SK2 (512 blocks)
    gemm_mfma<0, 2><<<dim3(8, 32, 2), 256, 0, stream>>>(AnT, t1T, P, 4096, 1024, 4096);
    reduce_k<2, 2, 1024><<<4096, 256, 0, stream>>>(P, h1, 4194304,
        b1, bn1_g, bn1_b, bn1_m, bn1_v);
    // G4 (swapped): t2T = w2T @ h1^T   M512 N4096 K1024, SK2 (256 blocks)
    gemm_mfma<0, 2><<<dim3(32, 4, 2), 256, 0, stream>>>(w2T, h1, P, 512, 4096, 1024);
    reduce_k<0, 2, 1><<<2048, 256, 0, stream>>>(P, t2T, 2097152,
        nullptr, nullptr, nullptr, nullptr, nullptr);
    // G5 (swapped): t2T @ AnT^T   M512 N4096 K4096, SK4 (512 blocks)
    gemm_mfma<0, 4><<<dim3(32, 4, 4), 256, 0, stream>>>(t2T, AnT, P, 512, 4096, 4096);
    reduce_pool_kernel<4><<<2048, 256, 0, stream>>>(
        P, pooled, b2, bn2_g, bn2_b, bn2_m, bn2_v);

    finalize_kernel<<<1, 512, 0, stream>>>(pooled, w_attn, b_attn, out);
}